// Round 1
// baseline (45.949 us; speedup 1.0000x reference)
//
#include <hip/hip_runtime.h>

// out[n, d] = x[n, d] * weight[d] + bias[d]
// x: (8192, 4096) fp32, weight/bias: (4096,) fp32, out: (8192, 4096) fp32.
// Memory-bound: 128 MiB read + 128 MiB write -> roofline ~42 us @ 6.3 TB/s.

constexpr int kD = 4096;
constexpr int kTokens = 8192;
constexpr long long kN = (long long)kTokens * kD;      // 33554432 elements
constexpr int kNVec = (int)(kN / 4);                   // 8388608 float4s
constexpr int kDVec = kD / 4;                          // 1024 float4s per row

__global__ __launch_bounds__(256) void DiagonalLinear_kernel(
    const float* __restrict__ x,
    const float* __restrict__ w,
    const float* __restrict__ b,
    float* __restrict__ out) {
    const float4* __restrict__ x4 = reinterpret_cast<const float4*>(x);
    const float4* __restrict__ w4 = reinterpret_cast<const float4*>(w);
    const float4* __restrict__ b4 = reinterpret_cast<const float4*>(b);
    float4* __restrict__ o4 = reinterpret_cast<float4*>(out);

    const int start = blockIdx.x * blockDim.x + threadIdx.x;
    const int stride = gridDim.x * blockDim.x;  // 524288 = multiple of kDVec

    // stride % kDVec == 0 -> column index is invariant across the loop.
    const int c = start & (kDVec - 1);
    const float4 wv = w4[c];
    const float4 bv = b4[c];

    for (int i = start; i < kNVec; i += stride) {
        float4 xv = x4[i];
        float4 ov;
        ov.x = fmaf(xv.x, wv.x, bv.x);
        ov.y = fmaf(xv.y, wv.y, bv.y);
        ov.z = fmaf(xv.z, wv.z, bv.z);
        ov.w = fmaf(xv.w, wv.w, bv.w);
        o4[i] = ov;
    }
}

extern "C" void kernel_launch(void* const* d_in, const int* in_sizes, int n_in,
                              void* d_out, int out_size, void* d_ws, size_t ws_size,
                              hipStream_t stream) {
    const float* x = (const float*)d_in[0];
    const float* w = (const float*)d_in[1];
    const float* b = (const float*)d_in[2];
    float* out = (float*)d_out;

    const int block = 256;
    const int grid = 2048;  // 2048*256 threads, grid-stride over 8388608 float4s
    DiagonalLinear_kernel<<<grid, block, 0, stream>>>(x, w, b, out);
}